// Round 1
// baseline (507.129 us; speedup 1.0000x reference)
//
#include <hip/hip_runtime.h>

#define DIM    2048
#define NE     64
#define NTOK   32768
#define BM     64
#define BK     32
#define NTHR   256
#define KTILES (DIM / BK)

struct SmemGemm { float xs[BK][BM + 4]; float ws[BK][NE + 4]; };
struct SmemEpi  { float ss[BM][NE + 1]; float mx[BM]; float zinv[BM]; float us[4][NE]; };
union Smem { SmemGemm g; SmemEpi e; };

__global__ __launch_bounds__(NTHR, 2)
void router_main(const float* __restrict__ x, const float* __restrict__ W,
                 float* __restrict__ out_idx, float* __restrict__ out_w,
                 float* __restrict__ gusage)
{
    __shared__ Smem sm;
    const int tid  = threadIdx.x;
    const int tok0 = blockIdx.x * BM;
    const int tg = tid & 15;       // token group: tokens 4*tg .. 4*tg+3
    const int eg = tid >> 4;       // expert group: experts 4*eg .. 4*eg+3

    float acc[4][4];
#pragma unroll
    for (int i = 0; i < 4; ++i)
#pragma unroll
        for (int j = 0; j < 4; ++j) acc[i][j] = 0.f;

    // staging mapping: 2048 floats per tile per matrix, 2 float4 per thread
    const int q1 = tid + NTHR;
    const int t0 = tid >> 3, d0 = (tid & 7) * 4;   // row (token/expert), col-within-tile
    const int t1 = q1  >> 3, d1 = (q1  & 7) * 4;

    const float* xb = x + (size_t)tok0 * DIM;

    float4 px0, px1, pw0, pw1;
    px0 = *(const float4*)&xb[t0 * DIM + d0];
    px1 = *(const float4*)&xb[t1 * DIM + d1];
    pw0 = *(const float4*)&W [t0 * DIM + d0];
    pw1 = *(const float4*)&W [t1 * DIM + d1];

    for (int kt = 0; kt < KTILES; ++kt) {
        __syncthreads();   // previous tile's compute reads done before overwrite
        // store staged tile, transposed to [dk][row]
        sm.g.xs[d0+0][t0] = px0.x; sm.g.xs[d0+1][t0] = px0.y;
        sm.g.xs[d0+2][t0] = px0.z; sm.g.xs[d0+3][t0] = px0.w;
        sm.g.xs[d1+0][t1] = px1.x; sm.g.xs[d1+1][t1] = px1.y;
        sm.g.xs[d1+2][t1] = px1.z; sm.g.xs[d1+3][t1] = px1.w;
        sm.g.ws[d0+0][t0] = pw0.x; sm.g.ws[d0+1][t0] = pw0.y;
        sm.g.ws[d0+2][t0] = pw0.z; sm.g.ws[d0+3][t0] = pw0.w;
        sm.g.ws[d1+0][t1] = pw1.x; sm.g.ws[d1+1][t1] = pw1.y;
        sm.g.ws[d1+2][t1] = pw1.z; sm.g.ws[d1+3][t1] = pw1.w;
        __syncthreads();

        if (kt + 1 < KTILES) {     // prefetch next tile; overlaps with compute below
            const int off = (kt + 1) * BK;
            px0 = *(const float4*)&xb[t0 * DIM + off + d0];
            px1 = *(const float4*)&xb[t1 * DIM + off + d1];
            pw0 = *(const float4*)&W [t0 * DIM + off + d0];
            pw1 = *(const float4*)&W [t1 * DIM + off + d1];
        }

#pragma unroll
        for (int dk = 0; dk < BK; ++dk) {
            float4 a = *(const float4*)&sm.g.xs[dk][4*tg];
            float4 b = *(const float4*)&sm.g.ws[dk][4*eg];
            float av[4] = {a.x, a.y, a.z, a.w};
            float bv[4] = {b.x, b.y, b.z, b.w};
#pragma unroll
            for (int i = 0; i < 4; ++i)
#pragma unroll
                for (int j = 0; j < 4; ++j)
                    acc[i][j] += av[i] * bv[j];
        }
    }

    // ---- epilogue: scores -> LDS, per-token top-2 + softmax, usage partials ----
    __syncthreads();   // all GEMM LDS reads done before aliasing with epi arrays
#pragma unroll
    for (int i = 0; i < 4; ++i)
#pragma unroll
        for (int j = 0; j < 4; ++j)
            sm.e.ss[4*tg + i][4*eg + j] = acc[i][j];
    __syncthreads();

    if (tid < BM) {
        const int t = tid;
        float v1 = -3.4e38f, v2 = -3.4e38f;
        int   i1 = 0, i2 = 0;
        for (int e = 0; e < NE; ++e) {
            float s = sm.e.ss[t][e];
            if (s > v1)      { v2 = v1; i2 = i1; v1 = s; i1 = e; }   // strict >: lowest index wins ties (jax semantics)
            else if (s > v2) { v2 = s;  i2 = e; }
        }
        float z = 0.f;
        for (int e = 0; e < NE; ++e) z += __expf(sm.e.ss[t][e] - v1);
        sm.e.mx[t]   = v1;
        sm.e.zinv[t] = 1.f / z;

        const int gt = tok0 + t;
        out_idx[gt*2 + 0] = (float)i1;
        out_idx[gt*2 + 1] = (float)i2;
        float e21 = __expf(v2 - v1);
        float w1  = 1.f / (1.f + e21);
        out_w[gt*2 + 0] = w1;
        out_w[gt*2 + 1] = e21 * w1;
    }
    __syncthreads();

    {   // per-expert usage partial: thread (c,e) sums 16 tokens
        const int e = tid & 63;
        const int c = tid >> 6;
        float u = 0.f;
        const int tbeg = c * 16;
        for (int t = tbeg; t < tbeg + 16; ++t)
            u += __expf(sm.e.ss[t][e] - sm.e.mx[t]) * sm.e.zinv[t];
        sm.e.us[c][e] = u;
    }
    __syncthreads();
    if (tid < NE) {
        float u = sm.e.us[0][tid] + sm.e.us[1][tid] + sm.e.us[2][tid] + sm.e.us[3][tid];
        atomicAdd(&gusage[tid], u);
    }
}

__global__ void router_finalize(const float* __restrict__ gusage, float* __restrict__ out_aux)
{
    const int e = threadIdx.x;           // 64 threads = 1 wave
    float u = gusage[e] * (1.0f / (float)NTOK);
    float s = u * u;
#pragma unroll
    for (int off = 32; off > 0; off >>= 1)
        s += __shfl_down(s, off, 64);
    if (e == 0) out_aux[0] = (float)NE * s;
}

extern "C" void kernel_launch(void* const* d_in, const int* in_sizes, int n_in,
                              void* d_out, int out_size, void* d_ws, size_t ws_size,
                              hipStream_t stream)
{
    const float* x = (const float*)d_in[0];
    const float* W = (const float*)d_in[1];
    float* out     = (float*)d_out;
    float* out_idx = out;                 // [4,8192,2] as float
    float* out_w   = out + NTOK * 2;      // [4,8192,2]
    float* out_aux = out + NTOK * 4;      // scalar
    float* gusage  = (float*)d_ws;        // 64 floats

    hipMemsetAsync(d_ws, 0, NE * sizeof(float), stream);
    hipLaunchKernelGGL(router_main, dim3(NTOK / BM), dim3(NTHR), 0, stream,
                       x, W, out_idx, out_w, gusage);
    hipLaunchKernelGGL(router_finalize, dim3(1), dim3(NE), 0, stream, gusage, out_aux);
}

// Round 2
// 406.980 us; speedup vs baseline: 1.2461x; 1.2461x over previous
//
#include <hip/hip_runtime.h>

#define DIM   2048
#define NE    64
#define NTOK  32768
#define BM    64          // tokens per block
#define NTHR  256         // 4 waves
#define KW    (DIM/4)     // 512: k-range owned by each wave (split-K)
#define BK    32          // k per staging tile
#define NKT   (KW/BK)     // 16 staging iterations per wave
#define S     68          // LDS row stride in floats (64 + 4 pad)

// Wave-private staging buffers -> no __syncthreads in the main loop.
struct SmemGemm { float xs[4][BK*S]; float ws[4][BK*S]; };                 // 69632 B
struct SmemEpi  { float ps[4][BM*S]; float mx[BM]; float zinv[BM]; float us[4][NE]; };
union  Smem     { SmemGemm g; SmemEpi e; };

__global__ __launch_bounds__(NTHR, 2)
void router_main(const float* __restrict__ x, const float* __restrict__ W,
                 float* __restrict__ out_idx, float* __restrict__ out_w,
                 float* __restrict__ gusage)
{
    __shared__ Smem sm;
    const int tid  = threadIdx.x;
    const int w    = tid >> 6;        // wave id: owns k in [w*KW, (w+1)*KW)
    const int ln   = tid & 63;
    const int tok0 = blockIdx.x * BM;
    const int a    = ln & 7;          // token octet: tokens 8a..8a+7 (local)
    const int b    = ln >> 3;         // expert octet: experts 8b..8b+7

    // lane ln stages token row (tok0+ln) and expert row ln of its wave's k-slice
    const float* xr = x + (size_t)(tok0 + ln) * DIM + w * KW;
    const float* wr = W + (size_t)ln * DIM + w * KW;

    float* xs = sm.g.xs[w];
    float* ws = sm.g.ws[w];

    float4 px[8], pw[8];
#pragma unroll
    for (int j = 0; j < 8; ++j) {
        px[j] = *(const float4*)(xr + 4*j);
        pw[j] = *(const float4*)(wr + 4*j);
    }

    float acc[8][8];
#pragma unroll
    for (int i = 0; i < 8; ++i)
#pragma unroll
        for (int jj = 0; jj < 8; ++jj) acc[i][jj] = 0.f;

    for (int kt = 0; kt < NKT; ++kt) {
        // store staged tile in [k][row] layout (transpose); lane-linear -> 2-way = free
#pragma unroll
        for (int j = 0; j < 8; ++j) {
            const int k = 4*j;
            xs[(k+0)*S + ln] = px[j].x;
            xs[(k+1)*S + ln] = px[j].y;
            xs[(k+2)*S + ln] = px[j].z;
            xs[(k+3)*S + ln] = px[j].w;
            ws[(k+0)*S + ln] = pw[j].x;
            ws[(k+1)*S + ln] = pw[j].y;
            ws[(k+2)*S + ln] = pw[j].z;
            ws[(k+3)*S + ln] = pw[j].w;
        }
        // prefetch next tile (global latency hidden behind the 32-dk compute below)
        if (kt + 1 < NKT) {
            const int off = (kt + 1) * BK;
#pragma unroll
            for (int j = 0; j < 8; ++j) {
                px[j] = *(const float4*)(xr + off + 4*j);
                pw[j] = *(const float4*)(wr + off + 4*j);
            }
        }
        // 8x8 outer product: 4 ds_read_b128 per dk feed 64 FMAs (LDS:VALU balanced)
#pragma unroll 4
        for (int dk = 0; dk < BK; ++dk) {
            const float4 a0 = *(const float4*)&xs[dk*S + 8*a];
            const float4 a1 = *(const float4*)&xs[dk*S + 8*a + 4];
            const float4 b0 = *(const float4*)&ws[dk*S + 8*b];
            const float4 b1 = *(const float4*)&ws[dk*S + 8*b + 4];
            const float av[8] = {a0.x,a0.y,a0.z,a0.w,a1.x,a1.y,a1.z,a1.w};
            const float bv[8] = {b0.x,b0.y,b0.z,b0.w,b1.x,b1.y,b1.z,b1.w};
#pragma unroll
            for (int i = 0; i < 8; ++i)
#pragma unroll
                for (int jj = 0; jj < 8; ++jj)
                    acc[i][jj] += av[i] * bv[jj];
        }
    }

    // ---- epilogue: reduce split-K partials, top-2 + softmax, usage ----
    __syncthreads();                       // all waves done with staging LDS
    {
        float* ps = sm.e.ps[w];
#pragma unroll
        for (int i = 0; i < 8; ++i) {
            *(float4*)&ps[(8*a+i)*S + 8*b    ] = make_float4(acc[i][0],acc[i][1],acc[i][2],acc[i][3]);
            *(float4*)&ps[(8*a+i)*S + 8*b + 4] = make_float4(acc[i][4],acc[i][5],acc[i][6],acc[i][7]);
        }
    }
    __syncthreads();
    {   // reduce 4 k-partials into ps[0]
        const int t = tid & 63;
        const int q = tid >> 6;
        float* p0 = sm.e.ps[0];
#pragma unroll
        for (int e0 = 0; e0 < 16; ++e0) {
            const int idx = t*S + (q*16 + e0);
            p0[idx] += sm.e.ps[1][idx] + sm.e.ps[2][idx] + sm.e.ps[3][idx];
        }
    }
    __syncthreads();

    const float* sc = sm.e.ps[0];          // scores [64][S]
    if (tid < BM) {
        const int t = tid;
        float v1 = -3.4e38f, v2 = -3.4e38f;
        int   i1 = 0, i2 = 0;
        for (int e = 0; e < NE; ++e) {
            float s = sc[t*S + e];
            if (s > v1)      { v2 = v1; i2 = i1; v1 = s; i1 = e; }  // strict >: lowest index wins ties
            else if (s > v2) { v2 = s;  i2 = e; }
        }
        float z = 0.f;
        for (int e = 0; e < NE; ++e) z += __expf(sc[t*S + e] - v1);
        sm.e.mx[t]   = v1;
        sm.e.zinv[t] = 1.f / z;

        const int gt = tok0 + t;
        out_idx[gt*2 + 0] = (float)i1;
        out_idx[gt*2 + 1] = (float)i2;
        float e21 = __expf(v2 - v1);
        float w1  = 1.f / (1.f + e21);
        out_w[gt*2 + 0] = w1;
        out_w[gt*2 + 1] = e21 * w1;
    }
    __syncthreads();

    {   // per-expert usage partials: thread (c,e) sums 16 tokens
        const int e = tid & 63;
        const int c = tid >> 6;
        float u = 0.f;
        const int tbeg = c * 16;
        for (int t = tbeg; t < tbeg + 16; ++t)
            u += __expf(sc[t*S + e] - sm.e.mx[t]) * sm.e.zinv[t];
        sm.e.us[c][e] = u;
    }
    __syncthreads();
    if (tid < NE) {
        float u = sm.e.us[0][tid] + sm.e.us[1][tid] + sm.e.us[2][tid] + sm.e.us[3][tid];
        atomicAdd(&gusage[tid], u);
    }
}

__global__ void router_finalize(const float* __restrict__ gusage, float* __restrict__ out_aux)
{
    const int e = threadIdx.x;             // 64 threads = 1 wave
    float u = gusage[e] * (1.0f / (float)NTOK);
    float s = u * u;
#pragma unroll
    for (int off = 32; off > 0; off >>= 1)
        s += __shfl_down(s, off, 64);
    if (e == 0) out_aux[0] = (float)NE * s;
}

extern "C" void kernel_launch(void* const* d_in, const int* in_sizes, int n_in,
                              void* d_out, int out_size, void* d_ws, size_t ws_size,
                              hipStream_t stream)
{
    const float* x = (const float*)d_in[0];
    const float* W = (const float*)d_in[1];
    float* out     = (float*)d_out;
    float* out_idx = out;                 // [4,8192,2] as float
    float* out_w   = out + NTOK * 2;      // [4,8192,2]
    float* out_aux = out + NTOK * 4;      // scalar
    float* gusage  = (float*)d_ws;        // 64 floats

    hipMemsetAsync(d_ws, 0, NE * sizeof(float), stream);
    hipLaunchKernelGGL(router_main, dim3(NTOK / BM), dim3(NTHR), 0, stream,
                       x, W, out_idx, out_w, gusage);
    hipLaunchKernelGGL(router_finalize, dim3(1), dim3(NE), 0, stream, gusage, out_aux);
}

// Round 3
// 392.427 us; speedup vs baseline: 1.2923x; 1.0371x over previous
//
#include <hip/hip_runtime.h>

#define DIM    2048
#define NE     64
#define NTOK   32768
#define BM     64          // tokens per block
#define NTHR   256         // 4 waves
#define KW     512         // k-range per wave (split-K by 4)
#define NKC    16          // 512 / 32
#define S      68          // epilogue LDS row stride (64 + 4 pad)
#define WPLANE (NE*DIM)    // 131072 elements per bf16 plane of W

typedef __attribute__((ext_vector_type(8))) short short8;   // 8 bf16 in 4 VGPRs
typedef __attribute__((ext_vector_type(4))) float f32x4;    // MFMA C/D frag

union U4S8 { uint4 u; short8 s; };

// D = (e0 >> 16) | (e1 & 0xffff0000): pack two fp32-top-halves into one dword
__device__ __forceinline__ unsigned pack_hi16(unsigned e0, unsigned e1) {
    return __builtin_amdgcn_perm(e1, e0, 0x07060302u);
}

// Exact 3-way bf16 truncation split of 8 fp32 values (x = hi + mid + lo exactly:
// truncation leaves exactly the low mantissa bits; residual subtractions exact).
__device__ __forceinline__ void split8(const float4& a, const float4& b,
                                       short8& h, short8& m, short8& l) {
    const float f[8] = {a.x, a.y, a.z, a.w, b.x, b.y, b.z, b.w};
    unsigned hb[8], mb[8], lb[8];
#pragma unroll
    for (int j = 0; j < 8; ++j) {
        const unsigned xb = __float_as_uint(f[j]);
        const unsigned th = xb & 0xffff0000u;
        const float    rh = f[j] - __uint_as_float(th);
        const unsigned rb = __float_as_uint(rh);
        const unsigned tm = rb & 0xffff0000u;
        const float    rm = rh - __uint_as_float(tm);   // <= 8 significant bits: exact bf16
        hb[j] = th; mb[j] = tm; lb[j] = __float_as_uint(rm);
    }
    U4S8 H, M, L;
    H.u = make_uint4(pack_hi16(hb[0],hb[1]), pack_hi16(hb[2],hb[3]),
                     pack_hi16(hb[4],hb[5]), pack_hi16(hb[6],hb[7]));
    M.u = make_uint4(pack_hi16(mb[0],mb[1]), pack_hi16(mb[2],mb[3]),
                     pack_hi16(mb[4],mb[5]), pack_hi16(mb[6],mb[7]));
    L.u = make_uint4(pack_hi16(lb[0],lb[1]), pack_hi16(lb[2],lb[3]),
                     pack_hi16(lb[4],lb[5]), pack_hi16(lb[6],lb[7]));
    h = H.s; m = M.s; l = L.s;
}

// Pre-kernel: split W (fp32 [64][2048]) into 3 bf16 planes in d_ws, layout [plane][n][k]
__global__ void router_wsplit(const float* __restrict__ W, unsigned short* __restrict__ W3)
{
    const int i = blockIdx.x * 256 + threadIdx.x;     // 131072 total
    const float f = W[i];
    const unsigned xb = __float_as_uint(f);
    const unsigned th = xb & 0xffff0000u;
    const float    rh = f - __uint_as_float(th);
    const unsigned rb = __float_as_uint(rh);
    const unsigned tm = rb & 0xffff0000u;
    const float    rm = rh - __uint_as_float(tm);
    W3[i]            = (unsigned short)(th >> 16);
    W3[WPLANE + i]   = (unsigned short)(tm >> 16);
    W3[2*WPLANE + i] = (unsigned short)(__float_as_uint(rm) >> 16);
}

struct SmemEpi { float ps[4][BM * S]; float mx[BM]; float zinv[BM]; float us[4][NE]; };

#define MFMA_GROUP(AF, BF)                                                       \
    _Pragma("unroll") for (int nt = 0; nt < 4; ++nt)                             \
    _Pragma("unroll") for (int mt = 0; mt < 4; ++mt)                             \
        acc[mt][nt] = __builtin_amdgcn_mfma_f32_16x16x32_bf16(                   \
            AF[mt], BF[nt].s, acc[mt][nt], 0, 0, 0);

__global__ __launch_bounds__(NTHR, 2)
void router_main(const float* __restrict__ x, const unsigned short* __restrict__ W3,
                 float* __restrict__ out_idx, float* __restrict__ out_w,
                 float* __restrict__ gusage)
{
    __shared__ SmemEpi sm;
    const int tid  = threadIdx.x;
    const int w    = tid >> 6;        // wave id: k-range [w*KW, (w+1)*KW)
    const int ln   = tid & 63;
    const int q    = ln >> 4;         // quad: k-offset q*8 (A/B), row-group q*4 (C/D)
    const int c    = ln & 15;         // A row (token), B row (expert), C col (expert)
    const int tok0 = blockIdx.x * BM;
    const int kbase = w * KW + q * 8;

    // A-frag sources: 8 consecutive fp32 of token row (mt*16+c) -- no LDS round-trip
    const float* xr[4];
#pragma unroll
    for (int mt = 0; mt < 4; ++mt)
        xr[mt] = x + (size_t)(tok0 + mt*16 + c) * DIM + kbase;
    // B-frag sources: 8 consecutive bf16 of W3 plane row (nt*16+c); L2-resident
    const unsigned short* wr[4];
#pragma unroll
    for (int nt = 0; nt < 4; ++nt)
        wr[nt] = W3 + (size_t)(nt*16 + c) * DIM + kbase;

    f32x4 acc[4][4];
#pragma unroll
    for (int mt = 0; mt < 4; ++mt)
#pragma unroll
        for (int nt = 0; nt < 4; ++nt)
            acc[mt][nt] = (f32x4){0.f, 0.f, 0.f, 0.f};

    float4 xf0[4], xf1[4];
#pragma unroll
    for (int mt = 0; mt < 4; ++mt) {           // preload kc=0 x
        xf0[mt] = *(const float4*)(xr[mt]);
        xf1[mt] = *(const float4*)(xr[mt] + 4);
    }

    for (int kc = 0; kc < NKC; ++kc) {
        const int ko = kc * 32;
        // issue B-hi loads first (L2 latency hidden by the split VALU below)
        U4S8 bh[4];
#pragma unroll
        for (int nt = 0; nt < 4; ++nt) bh[nt].u = *(const uint4*)(wr[nt] + ko);

        // in-register exact split of this kc's x into 3 bf16 A-planes
        short8 ah[4], am[4], al[4];
#pragma unroll
        for (int mt = 0; mt < 4; ++mt) split8(xf0[mt], xf1[mt], ah[mt], am[mt], al[mt]);

        // prefetch next kc's x (HBM latency hidden behind 96 MFMAs)
        if (kc + 1 < NKC) {
#pragma unroll
            for (int mt = 0; mt < 4; ++mt) {
                xf0[mt] = *(const float4*)(xr[mt] + ko + 32);
                xf1[mt] = *(const float4*)(xr[mt] + ko + 36);
            }
        }

        U4S8 bm[4];
#pragma unroll
        for (int nt = 0; nt < 4; ++nt) bm[nt].u = *(const uint4*)(wr[nt] + WPLANE + ko);

        // pass-terms grouped by B plane: hh, mh, lh | hM, mM | hL  (dropped ~2^-32)
        MFMA_GROUP(ah, bh)
        MFMA_GROUP(am, bh)
        MFMA_GROUP(al, bh)

        U4S8 bl[4];
#pragma unroll
        for (int nt = 0; nt < 4; ++nt) bl[nt].u = *(const uint4*)(wr[nt] + 2*WPLANE + ko);

        MFMA_GROUP(ah, bm)
        MFMA_GROUP(am, bm)
        MFMA_GROUP(ah, bl)
    }

    // ---- epilogue: land split-K partials in LDS, reduce, top-2 + softmax + usage ----
    {
        float* ps = sm.ps[w];
#pragma unroll
        for (int mt = 0; mt < 4; ++mt)
#pragma unroll
            for (int r = 0; r < 4; ++r) {
                const int t = mt*16 + q*4 + r;      // C/D: row = quad*4 + reg
#pragma unroll
                for (int nt = 0; nt < 4; ++nt)
                    ps[t*S + nt*16 + c] = acc[mt][nt][r];
            }
    }
    __syncthreads();
    {   // reduce 4 k-partials into ps[0]
        const int t = tid & 63;
        const int qq = tid >> 6;
        float* p0 = sm.ps[0];
#pragma unroll
        for (int e0 = 0; e0 < 16; ++e0) {
            const int idx = t*S + (qq*16 + e0);
            p0[idx] += sm.ps[1][idx] + sm.ps[2][idx] + sm.ps[3][idx];
        }
    }
    __syncthreads();

    const float* sc = sm.ps[0];
    if (tid < BM) {
        const int t = tid;
        float v1 = -3.4e38f, v2 = -3.4e38f;
        int   i1 = 0, i2 = 0;
        for (int e = 0; e < NE; ++e) {
            float s = sc[t*S + e];
            if (s > v1)      { v2 = v1; i2 = i1; v1 = s; i1 = e; }  // strict >: lowest index wins ties
            else if (s > v2) { v2 = s;  i2 = e; }
        }
        float z = 0.f;
        for (int e = 0; e < NE; ++e) z += __expf(sc[t*S + e] - v1);
        sm.mx[t]   = v1;
        sm.zinv[t] = 1.f / z;

        const int gt = tok0 + t;
        out_idx[gt*2 + 0] = (float)i1;
        out_idx[gt*2 + 1] = (float)i2;
        float e21 = __expf(v2 - v1);
        float w1  = 1.f / (1.f + e21);
        out_w[gt*2 + 0] = w1;
        out_w[gt*2 + 1] = e21 * w1;
    }
    __syncthreads();

    {   // per-expert usage partials: thread (cc,e) sums 16 tokens
        const int e  = tid & 63;
        const int cc = tid >> 6;
        float u = 0.f;
        const int tbeg = cc * 16;
        for (int t = tbeg; t < tbeg + 16; ++t)
            u += __expf(sc[t*S + e] - sm.mx[t]) * sm.zinv[t];
        sm.us[cc][e] = u;
    }
    __syncthreads();
    if (tid < NE) {
        float u = sm.us[0][tid] + sm.us[1][tid] + sm.us[2][tid] + sm.us[3][tid];
        atomicAdd(&gusage[tid], u);
    }
}

__global__ void router_finalize(const float* __restrict__ gusage, float* __restrict__ out_aux)
{
    const int e = threadIdx.x;             // 64 threads = 1 wave
    float u = gusage[e] * (1.0f / (float)NTOK);
    float s = u * u;
#pragma unroll
    for (int off = 32; off > 0; off >>= 1)
        s += __shfl_down(s, off, 64);
    if (e == 0) out_aux[0] = (float)NE * s;
}

extern "C" void kernel_launch(void* const* d_in, const int* in_sizes, int n_in,
                              void* d_out, int out_size, void* d_ws, size_t ws_size,
                              hipStream_t stream)
{
    const float* x = (const float*)d_in[0];
    const float* W = (const float*)d_in[1];
    float* out     = (float*)d_out;
    float* out_idx = out;                 // [4,8192,2] as float
    float* out_w   = out + NTOK * 2;      // [4,8192,2]
    float* out_aux = out + NTOK * 4;      // scalar

    unsigned short* W3 = (unsigned short*)d_ws;                       // 3*131072 bf16 = 786432 B
    float* gusage = (float*)((char*)d_ws + 3 * WPLANE * sizeof(unsigned short));

    hipMemsetAsync(gusage, 0, NE * sizeof(float), stream);
    hipLaunchKernelGGL(router_wsplit, dim3(WPLANE / 256), dim3(256), 0, stream, W, W3);
    hipLaunchKernelGGL(router_main, dim3(NTOK / BM), dim3(NTHR), 0, stream,
                       x, W3, out_idx, out_w, gusage);
    hipLaunchKernelGGL(router_finalize, dim3(1), dim3(NE), 0, stream, gusage, out_aux);
}